// Round 12
// baseline (136.787 us; speedup 1.0000x reference)
//
#include <hip/hip_runtime.h>
#include <hip/hip_bf16.h>
#include <math.h>

#define NATOMS 1280
#define NHEAD 4
#define DHEAD 16
#define EEDGE 5120
#define MKV 12800
#define NLAYERS 4
#define NGRAPH 32
#define NPG 40      // atoms per graph
#define MPG 400     // kv per graph

// ---- one precompute kernel: EW GEMM + KV GEMM (head-major out) + agg zero ---
// blocks [0,320): EW tiles; [320,1120): KV tiles; [1120,1200): zero agg
__global__ __launch_bounds__(256) void precompute_kernel(
    const float* __restrict__ edge_attr, const float* __restrict__ Kin,
    const float* __restrict__ Vin, const float* __restrict__ We,
    const float* __restrict__ Wk, const float* __restrict__ Wv,
    float* __restrict__ EW, float* __restrict__ Khh, float* __restrict__ Vhh,
    float* __restrict__ agg) {
  __shared__ float aT[64][132];  // A tile transposed [k][row], padded
  __shared__ float wS[64][64];
  const int b = blockIdx.x, t = threadIdx.x;

  if (b < 320) {  // ---- EW[l] = edge_attr @ We[l], 64-row tiles, K=16 ----
    int l = b / 80, et = b % 80;
    const float* A = edge_attr + (size_t)et * 64 * 16;
    const float* W = We + l * 1024;
    float* C = EW + ((size_t)l * EEDGE + et * 64) * 64;
    {
      int r = t >> 2, c0 = (t & 3) * 4;
      float4 v = *(const float4*)(A + r * 16 + c0);
      aT[c0 + 0][r] = v.x; aT[c0 + 1][r] = v.y;
      aT[c0 + 2][r] = v.z; aT[c0 + 3][r] = v.w;
      float4 w = ((const float4*)W)[t];
      *(float4*)&wS[t >> 4][(t & 15) * 4] = w;
    }
    __syncthreads();
    const int rb = (t >> 4) * 4, cb = (t & 15) * 4;
    float acc[4][4] = {};
#pragma unroll
    for (int k = 0; k < 16; ++k) {
      float4 a = *(const float4*)&aT[k][rb];
      float4 w = *(const float4*)&wS[k][cb];
      acc[0][0] += a.x * w.x; acc[0][1] += a.x * w.y; acc[0][2] += a.x * w.z; acc[0][3] += a.x * w.w;
      acc[1][0] += a.y * w.x; acc[1][1] += a.y * w.y; acc[1][2] += a.y * w.z; acc[1][3] += a.y * w.w;
      acc[2][0] += a.z * w.x; acc[2][1] += a.z * w.y; acc[2][2] += a.z * w.z; acc[2][3] += a.z * w.w;
      acc[3][0] += a.w * w.x; acc[3][1] += a.w * w.y; acc[3][2] += a.w * w.z; acc[3][3] += a.w * w.w;
    }
#pragma unroll
    for (int i = 0; i < 4; ++i)
      *(float4*)(C + (size_t)(rb + i) * 64 + cb) =
          make_float4(acc[i][0], acc[i][1], acc[i][2], acc[i][3]);
  } else if (b < 1120) {  // ---- Khh/Vhh = {K,V}@{Wk,Wv}[l], head-major out ---
    int tid = b - 320;
    int gy = tid / 100, rt = tid % 100;
    int which = gy >> 2, l = gy & 3;
    const float* A = (which ? Vin : Kin) + (size_t)rt * 128 * 64;
    const float* W = (which ? Wv : Wk) + l * 4096;
    float* C = which ? Vhh : Khh;
    for (int i = t; i < 2048; i += 256) {  // 128 rows x 16 float4, transpose
      int r = i >> 4, c0 = (i & 15) * 4;
      float4 v = *(const float4*)(A + r * 64 + c0);
      aT[c0 + 0][r] = v.x; aT[c0 + 1][r] = v.y;
      aT[c0 + 2][r] = v.z; aT[c0 + 3][r] = v.w;
    }
    for (int i = t; i < 1024; i += 256) {
      float4 v = ((const float4*)W)[i];
      *(float4*)&wS[i >> 4][(i & 15) * 4] = v;
    }
    __syncthreads();
    const int rb = (t >> 4) * 8, cb = (t & 15) * 4;
    float acc[8][4] = {};
#pragma unroll 4
    for (int k = 0; k < 64; ++k) {
      float4 a0 = *(const float4*)&aT[k][rb];
      float4 a1 = *(const float4*)&aT[k][rb + 4];
      float4 w = *(const float4*)&wS[k][cb];
      acc[0][0] += a0.x * w.x; acc[0][1] += a0.x * w.y; acc[0][2] += a0.x * w.z; acc[0][3] += a0.x * w.w;
      acc[1][0] += a0.y * w.x; acc[1][1] += a0.y * w.y; acc[1][2] += a0.y * w.z; acc[1][3] += a0.y * w.w;
      acc[2][0] += a0.z * w.x; acc[2][1] += a0.z * w.y; acc[2][2] += a0.z * w.z; acc[2][3] += a0.z * w.w;
      acc[3][0] += a0.w * w.x; acc[3][1] += a0.w * w.y; acc[3][2] += a0.w * w.z; acc[3][3] += a0.w * w.w;
      acc[4][0] += a1.x * w.x; acc[4][1] += a1.x * w.y; acc[4][2] += a1.x * w.z; acc[4][3] += a1.x * w.w;
      acc[5][0] += a1.y * w.x; acc[5][1] += a1.y * w.y; acc[5][2] += a1.y * w.z; acc[5][3] += a1.y * w.w;
      acc[6][0] += a1.z * w.x; acc[6][1] += a1.z * w.y; acc[6][2] += a1.z * w.z; acc[6][3] += a1.z * w.w;
      acc[7][0] += a1.w * w.x; acc[7][1] += a1.w * w.y; acc[7][2] += a1.w * w.z; acc[7][3] += a1.w * w.w;
    }
    // head-major store: C[((l*4+head)*MKV + row)*16 + d]
    int head = cb >> 4, dd = cb & 15;
    size_t base = ((size_t)(l * 4 + head) * MKV + (size_t)rt * 128 + rb) * 16 + dd;
#pragma unroll
    for (int i = 0; i < 8; ++i)
      *(float4*)(C + base + (size_t)i * 16) =
          make_float4(acc[i][0], acc[i][1], acc[i][2], acc[i][3]);
  } else {  // ---- zero agg (all layers): 4*1280*64 floats = 81920 float4 ----
    int i = (b - 1120) * 256 + t;
    float4 z = make_float4(0.f, 0.f, 0.f, 0.f);
    for (int j = i; j < NLAYERS * NATOMS * 16; j += 80 * 256)
      ((float4*)agg)[j] = z;
  }
}

// -- per layer: edge messages + scatter-add, AND init xout = xin (residual) ---
__global__ void edge_copy_kernel(const float* __restrict__ xin,
                                 const float* __restrict__ EWl,
                                 const int* __restrict__ src,
                                 const int* __restrict__ dst,
                                 float* __restrict__ agg,
                                 float* __restrict__ xout) {
  int idx = blockIdx.x * 256 + threadIdx.x;  // covers E*64 = 327680
  if (idx < NATOMS * 64) xout[idx] = xin[idx];
  int e = idx >> 6, f = idx & 63;
  float m = xin[src[e] * 64 + f] + EWl[idx];
  m = m / (1.f + __expf(-m));  // silu
  atomicAdd(&agg[dst[e] * 64 + f], m);
}

// -- barrier-free wave attention: one 64-lane wave per (row, head) ------------
//    grid (1280, 4); no LDS, no __syncthreads; all-register + shfl.
__global__ __launch_bounds__(64) void wave_attn_kernel(
    const float* __restrict__ xin, const float* __restrict__ agg,
    const float* __restrict__ Wm, const float* __restrict__ Wq,
    const float* __restrict__ Wo, const float* __restrict__ Khh,
    const float* __restrict__ Vhh, float* __restrict__ xout) {
  const int n = blockIdx.x;        // atom row
  const int hd = blockIdx.y;       // head
  const int g = n / NPG;
  const int lane = threadIdx.x;
  const int hoff = hd * DHEAD;
  const float* Kp = Khh + ((size_t)hd * MKV + (size_t)g * MPG) * 16;
  const float* Vp = Vhh + ((size_t)hd * MKV + (size_t)g * MPG) * 16;

  // h[lane] = x[n][lane] + sum_k agg[n][k] * Wm[k][lane]   (shfl-broadcast)
  float a = agg[n * 64 + lane];
  float h = xin[n * 64 + lane];
#pragma unroll 16
  for (int k = 0; k < 64; ++k) h += __shfl(a, k) * Wm[k * 64 + lane];

  // Q[hoff + (lane&15)] partial (4-fold redundant across lane groups)
  const int d0 = lane & 15;
  float qa = 0.f;
#pragma unroll 16
  for (int f = 0; f < 64; ++f) qa += __shfl(h, f) * Wq[f * 64 + hoff + d0];
  qa *= 0.25f;
  float Q[16];
#pragma unroll
  for (int d = 0; d < 16; ++d) Q[d] = __shfl(qa, d);

  // scores: lane owns k = it*64+lane; K rows read as 4x float4 (coalesced)
  float s[7];
#pragma unroll
  for (int it = 0; it < 7; ++it) {
    int k = it * 64 + lane;
    float acc = -1e30f;
    if (k < MPG) {
      const float4* kr = (const float4*)(Kp + (size_t)k * 16);
      float4 k0 = kr[0], k1 = kr[1], k2 = kr[2], k3 = kr[3];
      acc = Q[0] * k0.x + Q[1] * k0.y + Q[2] * k0.z + Q[3] * k0.w +
            Q[4] * k1.x + Q[5] * k1.y + Q[6] * k1.z + Q[7] * k1.w +
            Q[8] * k2.x + Q[9] * k2.y + Q[10] * k2.z + Q[11] * k2.w +
            Q[12] * k3.x + Q[13] * k3.y + Q[14] * k3.z + Q[15] * k3.w;
    }
    s[it] = acc;
  }
  // row max across regs + lanes
  float m = s[0];
#pragma unroll
  for (int it = 1; it < 7; ++it) m = fmaxf(m, s[it]);
  for (int off = 32; off; off >>= 1) m = fmaxf(m, __shfl_xor(m, off));

  // exp + PV in one pass (V rows 4x float4, coalesced)
  float o[16] = {0.f, 0.f, 0.f, 0.f, 0.f, 0.f, 0.f, 0.f,
                 0.f, 0.f, 0.f, 0.f, 0.f, 0.f, 0.f, 0.f};
  float sum = 0.f;
#pragma unroll
  for (int it = 0; it < 7; ++it) {
    int k = it * 64 + lane;
    if (k < MPG) {
      float p = __expf(s[it] - m);
      sum += p;
      const float4* vr = (const float4*)(Vp + (size_t)k * 16);
      float4 v0 = vr[0], v1 = vr[1], v2 = vr[2], v3 = vr[3];
      o[0] += p * v0.x;  o[1] += p * v0.y;  o[2] += p * v0.z;  o[3] += p * v0.w;
      o[4] += p * v1.x;  o[5] += p * v1.y;  o[6] += p * v1.z;  o[7] += p * v1.w;
      o[8] += p * v2.x;  o[9] += p * v2.y;  o[10] += p * v2.z; o[11] += p * v2.w;
      o[12] += p * v3.x; o[13] += p * v3.y; o[14] += p * v3.z; o[15] += p * v3.w;
    }
  }
  for (int off = 32; off; off >>= 1) sum += __shfl_xor(sum, off);
#pragma unroll
  for (int d = 0; d < 16; ++d)
    for (int off = 32; off; off >>= 1) o[d] += __shfl_xor(o[d], off);
  const float inv = 1.0f / sum;

  // out-projection for this head; residual handled by edge_copy's xout=xin
  float outv = 0.f;
#pragma unroll
  for (int d = 0; d < 16; ++d)
    outv += o[d] * inv * Wo[(hoff + d) * 64 + lane];
  atomicAdd(&xout[n * 64 + lane], outv);
}

extern "C" void kernel_launch(void* const* d_in, const int* in_sizes, int n_in,
                              void* d_out, int out_size, void* d_ws, size_t ws_size,
                              hipStream_t stream) {
  const float* x        = (const float*)d_in[0];
  const float* edge_attr= (const float*)d_in[1];
  const float* K        = (const float*)d_in[2];
  const float* V        = (const float*)d_in[3];
  const float* We       = (const float*)d_in[4];
  const float* Wm       = (const float*)d_in[5];
  const float* Wq       = (const float*)d_in[6];
  const float* Wk       = (const float*)d_in[7];
  const float* Wv       = (const float*)d_in[8];
  const float* Wo       = (const float*)d_in[9];
  const int*   eidx     = (const int*)d_in[10];
  const int*   src      = eidx;
  const int*   dst      = eidx + EEDGE;

  float* w    = (float*)d_ws;
  float* Khh  = w;                                   // [4 layers][4 heads][12800][16]
  float* Vhh  = Khh + (size_t)NLAYERS * MKV * 64;
  float* EW   = Vhh + (size_t)NLAYERS * MKV * 64;    // 4*5120*64
  float* agg  = EW + (size_t)NLAYERS * EEDGE * 64;   // 4*1280*64
  float* xA   = agg + (size_t)NLAYERS * NATOMS * 64;
  float* xB   = xA + NATOMS * 64;

  // one precompute kernel: EW + head-major Khh/Vhh + agg zeroing (all layers)
  precompute_kernel<<<1200, 256, 0, stream>>>(edge_attr, K, V, We, Wk, Wv,
                                              EW, Khh, Vhh, agg);

  const float* xin = x;
  for (int l = 0; l < NLAYERS; ++l) {
    float* aggl = agg + (size_t)l * NATOMS * 64;
    float* xout = (l == NLAYERS - 1) ? (float*)d_out : ((l & 1) ? xB : xA);
    edge_copy_kernel<<<EEDGE * 64 / 256, 256, 0, stream>>>(
        xin, EW + (size_t)l * EEDGE * 64, src, dst, aggl, xout);
    wave_attn_kernel<<<dim3(NATOMS, NHEAD), 64, 0, stream>>>(
        xin, aggl, Wm + l * 4096, Wq + l * 4096, Wo + l * 4096,
        Khh + (size_t)l * MKV * 64, Vhh + (size_t)l * MKV * 64, xout);
    xin = xout;
  }
}